// Round 2
// baseline (1876.953 us; speedup 1.0000x reference)
//
#include <hip/hip_runtime.h>

// ---------------------------------------------------------------------------
// Dims (fixed by the reference)
// ---------------------------------------------------------------------------
#define Bv 16
#define Kv 12
#define Lv 8
#define Pv 24
#define Dv 768
#define H1v 384
#define Vv 44
#define KLv 96          // K*L
#define N1v 1536        // B*K*L
#define BKv 192         // B*K
#define G1v 2304        // 3*D
#define G2v 1152        // 3*H1
#define G3v 1536        // 4*H1

typedef __bf16 bf16_t;
typedef __attribute__((ext_vector_type(8))) __bf16 bf16x8;
typedef __attribute__((ext_vector_type(4))) float f32x4;

__device__ __forceinline__ float sigmf(float x){ return 1.0f/(1.0f + __expf(-x)); }

// ---------------------------------------------------------------------------
// Prep kernels
// ---------------------------------------------------------------------------
__global__ void cast_bf16_kernel(const float* __restrict__ src, bf16_t* __restrict__ dst, int n4){
    int i = blockIdx.x*256 + threadIdx.x;
    if (i < n4){
        float4 f = reinterpret_cast<const float4*>(src)[i];
        bf16_t o[4] = {(bf16_t)f.x,(bf16_t)f.y,(bf16_t)f.z,(bf16_t)f.w};
        reinterpret_cast<ushort4*>(dst)[i] = *reinterpret_cast<ushort4*>(o);
    }
}

__global__ void transpose_kernel(const float* __restrict__ src, float* __restrict__ dst, int R, int C){
    int i = blockIdx.x*256 + threadIdx.x;
    if (i < R*C){ int r = i/C, c = i - r*C; dst[c*R + r] = src[i]; }
}

// E[v][g] = sum_k emb[v,k]*Wih[g,k] + bih[g]   -> [44, 2304]
__global__ void ebuild_kernel(const float* __restrict__ emb, const float* __restrict__ Wih,
                              const float* __restrict__ bih, float* __restrict__ E){
    __shared__ float ev[Dv];
    int v = blockIdx.x;
    for (int i=threadIdx.x;i<Dv;i+=256) ev[i] = emb[v*Dv+i];
    __syncthreads();
    int w = threadIdx.x>>6, lane = threadIdx.x&63;
    for (int gi=0; gi<16; gi++){
        int g = blockIdx.y*64 + w*16 + gi;
        float s = 0.f;
        for (int k=lane;k<Dv;k+=64) s += ev[k]*Wih[g*Dv+k];
        #pragma unroll
        for (int off=32;off;off>>=1) s += __shfl_down(s,off);
        if (lane==0) E[v*G1v+g] = s + bih[g];
    }
}

// ---------------------------------------------------------------------------
// Stage-1 GRU step: batch 1536, hidden 768.
// Block = 64 seq rows x 64 hidden cols (-> 192 gate cols). 4 waves.
// ---------------------------------------------------------------------------
__launch_bounds__(256, 2)
__global__ void gru_step_kernel(const float* __restrict__ h_old,
                                float* __restrict__ h_new,
                                const bf16_t* __restrict__ Whh,   // [2304,768] bf16
                                const float* __restrict__ E,      // [44,2304]
                                const float* __restrict__ bhh,    // [2304]
                                const int* __restrict__ paths,    // [16,12,8,24]
                                const int* __restrict__ src_idx,  // [16]
                                int tstep)
{
    __shared__ bf16_t As[64][40];
    __shared__ bf16_t Bs[192][40];
    __shared__ float  ghs[64][192];

    const int tid = threadIdx.x;
    const int s0 = blockIdx.x*64, c0 = blockIdx.y*64;
    const int w = tid>>6, lane = tid&63;
    const int wm = w&1, wn = w>>1;
    const int arow = tid>>2, ac8 = (tid&3)*8;

    f32x4 acc[2][6];
    #pragma unroll
    for (int i=0;i<2;i++)
        #pragma unroll
        for (int j=0;j<6;j++) acc[i][j] = f32x4{0.f,0.f,0.f,0.f};

    for (int kk=0; kk<Dv; kk+=32){
        {
            const float4 f0 = *reinterpret_cast<const float4*>(&h_old[(s0+arow)*Dv + kk + ac8]);
            const float4 f1 = *reinterpret_cast<const float4*>(&h_old[(s0+arow)*Dv + kk + ac8 + 4]);
            bf16_t* ad = &As[arow][ac8];
            ad[0]=(bf16_t)f0.x; ad[1]=(bf16_t)f0.y; ad[2]=(bf16_t)f0.z; ad[3]=(bf16_t)f0.w;
            ad[4]=(bf16_t)f1.x; ad[5]=(bf16_t)f1.y; ad[6]=(bf16_t)f1.z; ad[7]=(bf16_t)f1.w;
        }
        #pragma unroll
        for (int i=0;i<3;i++){
            int idx = tid + 256*i;            // 0..767
            int row = idx>>2, c8 = (idx&3)*8; // row 0..191
            int grow = (row>>6)*Dv + c0 + (row&63);
            *reinterpret_cast<uint4*>(&Bs[row][c8]) =
                *reinterpret_cast<const uint4*>(&Whh[grow*Dv + kk + c8]);
        }
        __syncthreads();
        const int fr = lane&15, fk = (lane>>4)*8;
        bf16x8 afr[2], bfr[6];
        #pragma unroll
        for (int mt=0;mt<2;mt++) afr[mt] = *reinterpret_cast<const bf16x8*>(&As[wm*32+mt*16+fr][fk]);
        #pragma unroll
        for (int nt=0;nt<6;nt++) bfr[nt] = *reinterpret_cast<const bf16x8*>(&Bs[wn*96+nt*16+fr][fk]);
        #pragma unroll
        for (int mt=0;mt<2;mt++)
            #pragma unroll
            for (int nt=0;nt<6;nt++)
                acc[mt][nt] = __builtin_amdgcn_mfma_f32_16x16x32_bf16(afr[mt], bfr[nt], acc[mt][nt],0,0,0);
        __syncthreads();
    }
    {
        const int fj = lane&15, fi4 = (lane>>4)*4;
        #pragma unroll
        for (int mt=0;mt<2;mt++)
            #pragma unroll
            for (int nt=0;nt<6;nt++)
                #pragma unroll
                for (int r=0;r<4;r++)
                    ghs[wm*32+mt*16+fi4+r][wn*96+nt*16+fj] = acc[mt][nt][r];
    }
    __syncthreads();
    #pragma unroll
    for (int i=0;i<16;i++){
        int idx = tid + 256*i;   // 0..4095
        int row = idx>>6, j = idx&63;
        int s = s0 + row;
        int b = s / KLv;
        int rest = s - b*KLv;
        int tok = paths[(src_idx[b]*KLv + rest)*Pv + tstep];
        const float* Erow = &E[tok*G1v];
        int cj = c0 + j;
        float gr  = Erow[cj]        + ghs[row][j]      + bhh[cj];
        float gz  = Erow[Dv+cj]     + ghs[row][64+j]   + bhh[Dv+cj];
        float gnx = Erow[2*Dv+cj];
        float ghn = ghs[row][128+j] + bhh[2*Dv+cj];
        float r = sigmf(gr), z = sigmf(gz);
        float n = tanhf(gnx + r*ghn);
        float hprev = h_old[s*Dv + cj];
        h_new[s*Dv + cj] = (1.f - z)*n + z*hprev;
    }
}

// ---------------------------------------------------------------------------
// Generic BT-GEMM: C[M,N] = A[M,K] @ B[N,K]^T (+bias[N]) (+add[M,N])
// CT = float or bf16_t output; optional relu.
// ---------------------------------------------------------------------------
template<typename CT, bool RELU>
__launch_bounds__(256, 4)
__global__ void gemm_bt_kernel(const float* __restrict__ A, const bf16_t* __restrict__ B,
                               const float* __restrict__ bias, const float* __restrict__ add,
                               CT* __restrict__ C, int N, int K)
{
    __shared__ bf16_t As[64][40];
    __shared__ bf16_t Bs[64][40];
    const int tid = threadIdx.x;
    const int m0 = blockIdx.x*64, n0 = blockIdx.y*64;
    const int w = tid>>6, lane = tid&63;
    const int wm = w&1, wn = w>>1;
    const int arow = tid>>2, ac8 = (tid&3)*8;
    f32x4 acc[2][2];
    #pragma unroll
    for (int i=0;i<2;i++)
        #pragma unroll
        for (int j=0;j<2;j++) acc[i][j] = f32x4{0.f,0.f,0.f,0.f};

    for (int kk=0; kk<K; kk+=32){
        {
            const float4 f0 = *reinterpret_cast<const float4*>(&A[(size_t)(m0+arow)*K + kk + ac8]);
            const float4 f1 = *reinterpret_cast<const float4*>(&A[(size_t)(m0+arow)*K + kk + ac8 + 4]);
            bf16_t* ad = &As[arow][ac8];
            ad[0]=(bf16_t)f0.x; ad[1]=(bf16_t)f0.y; ad[2]=(bf16_t)f0.z; ad[3]=(bf16_t)f0.w;
            ad[4]=(bf16_t)f1.x; ad[5]=(bf16_t)f1.y; ad[6]=(bf16_t)f1.z; ad[7]=(bf16_t)f1.w;
        }
        *reinterpret_cast<uint4*>(&Bs[arow][ac8]) =
            *reinterpret_cast<const uint4*>(&B[(size_t)(n0+arow)*K + kk + ac8]);
        __syncthreads();
        const int fr = lane&15, fk = (lane>>4)*8;
        bf16x8 a0 = *reinterpret_cast<const bf16x8*>(&As[wm*32+fr][fk]);
        bf16x8 a1 = *reinterpret_cast<const bf16x8*>(&As[wm*32+16+fr][fk]);
        bf16x8 b0 = *reinterpret_cast<const bf16x8*>(&Bs[wn*32+fr][fk]);
        bf16x8 b1 = *reinterpret_cast<const bf16x8*>(&Bs[wn*32+16+fr][fk]);
        acc[0][0] = __builtin_amdgcn_mfma_f32_16x16x32_bf16(a0,b0,acc[0][0],0,0,0);
        acc[0][1] = __builtin_amdgcn_mfma_f32_16x16x32_bf16(a0,b1,acc[0][1],0,0,0);
        acc[1][0] = __builtin_amdgcn_mfma_f32_16x16x32_bf16(a1,b0,acc[1][0],0,0,0);
        acc[1][1] = __builtin_amdgcn_mfma_f32_16x16x32_bf16(a1,b1,acc[1][1],0,0,0);
        __syncthreads();
    }
    const int fj = lane&15, fi4 = (lane>>4)*4;
    #pragma unroll
    for (int mt=0;mt<2;mt++)
        #pragma unroll
        for (int nt=0;nt<2;nt++){
            int gr = m0 + wm*32 + mt*16 + fi4;
            int gc = n0 + wn*32 + nt*16 + fj;
            float bv = bias ? bias[gc] : 0.f;
            #pragma unroll
            for (int r=0;r<4;r++){
                float v = acc[mt][nt][r] + bv;
                if (add) v += add[(size_t)(gr+r)*N + gc];
                if (RELU) v = fmaxf(v, 0.f);
                C[(size_t)(gr+r)*N + gc] = (CT)v;
            }
        }
}

// ---------------------------------------------------------------------------
// Stage-2 bidirectional GRU step: batch 192, hidden 384. grid (3,6,2).
// xg is bf16.
// ---------------------------------------------------------------------------
__launch_bounds__(256, 2)
__global__ void gru1_step_kernel(const float* __restrict__ hof, const float* __restrict__ hob,
                                 float* __restrict__ hnf, float* __restrict__ hnb,
                                 const bf16_t* __restrict__ Whf, const bf16_t* __restrict__ Whb,
                                 const bf16_t* __restrict__ xgf, const bf16_t* __restrict__ xgb,
                                 const float* __restrict__ bhf, const float* __restrict__ bhb,
                                 float* __restrict__ ymf, float* __restrict__ ymb,
                                 int tstep, int is_first)
{
    __shared__ bf16_t As[64][40];
    __shared__ bf16_t Bs[192][40];
    __shared__ float  ghs[64][192];
    const int dir = blockIdx.z;
    const float* h_old = dir ? hob : hof;
    float* h_new = dir ? hnb : hnf;
    const bf16_t* Whh = dir ? Whb : Whf;
    const bf16_t* xg = dir ? xgb : xgf;
    const float* bhh = dir ? bhb : bhf;
    float* ymax = dir ? ymb : ymf;
    const int lidx = dir ? (Lv-1 - tstep) : tstep;

    const int tid = threadIdx.x;
    const int s0 = blockIdx.x*64, c0 = blockIdx.y*64;
    const int w = tid>>6, lane = tid&63;
    const int wm = w&1, wn = w>>1;
    const int arow = tid>>2, ac8 = (tid&3)*8;

    f32x4 acc[2][6];
    #pragma unroll
    for (int i=0;i<2;i++)
        #pragma unroll
        for (int j=0;j<6;j++) acc[i][j] = f32x4{0.f,0.f,0.f,0.f};

    for (int kk=0; kk<H1v; kk+=32){
        {
            const float4 f0 = *reinterpret_cast<const float4*>(&h_old[(s0+arow)*H1v + kk + ac8]);
            const float4 f1 = *reinterpret_cast<const float4*>(&h_old[(s0+arow)*H1v + kk + ac8 + 4]);
            bf16_t* ad = &As[arow][ac8];
            ad[0]=(bf16_t)f0.x; ad[1]=(bf16_t)f0.y; ad[2]=(bf16_t)f0.z; ad[3]=(bf16_t)f0.w;
            ad[4]=(bf16_t)f1.x; ad[5]=(bf16_t)f1.y; ad[6]=(bf16_t)f1.z; ad[7]=(bf16_t)f1.w;
        }
        #pragma unroll
        for (int i=0;i<3;i++){
            int idx = tid + 256*i;
            int row = idx>>2, c8 = (idx&3)*8;
            int grow = (row>>6)*H1v + c0 + (row&63);
            *reinterpret_cast<uint4*>(&Bs[row][c8]) =
                *reinterpret_cast<const uint4*>(&Whh[grow*H1v + kk + c8]);
        }
        __syncthreads();
        const int fr = lane&15, fk = (lane>>4)*8;
        bf16x8 afr[2], bfr[6];
        #pragma unroll
        for (int mt=0;mt<2;mt++) afr[mt] = *reinterpret_cast<const bf16x8*>(&As[wm*32+mt*16+fr][fk]);
        #pragma unroll
        for (int nt=0;nt<6;nt++) bfr[nt] = *reinterpret_cast<const bf16x8*>(&Bs[wn*96+nt*16+fr][fk]);
        #pragma unroll
        for (int mt=0;mt<2;mt++)
            #pragma unroll
            for (int nt=0;nt<6;nt++)
                acc[mt][nt] = __builtin_amdgcn_mfma_f32_16x16x32_bf16(afr[mt], bfr[nt], acc[mt][nt],0,0,0);
        __syncthreads();
    }
    {
        const int fj = lane&15, fi4 = (lane>>4)*4;
        #pragma unroll
        for (int mt=0;mt<2;mt++)
            #pragma unroll
            for (int nt=0;nt<6;nt++)
                #pragma unroll
                for (int r=0;r<4;r++)
                    ghs[wm*32+mt*16+fi4+r][wn*96+nt*16+fj] = acc[mt][nt][r];
    }
    __syncthreads();
    #pragma unroll
    for (int i=0;i<16;i++){
        int idx = tid + 256*i;
        int row = idx>>6, j = idx&63;
        int s = s0 + row;
        int cj = c0 + j;
        const bf16_t* xrow = &xg[(size_t)(s*Lv + lidx)*G2v];
        float gr  = (float)xrow[cj]       + ghs[row][j]      + bhh[cj];
        float gz  = (float)xrow[H1v+cj]   + ghs[row][64+j]   + bhh[H1v+cj];
        float gnx = (float)xrow[2*H1v+cj];
        float ghn = ghs[row][128+j]       + bhh[2*H1v+cj];
        float r = sigmf(gr), z = sigmf(gz);
        float n = tanhf(gnx + r*ghn);
        float hv = (1.f - z)*n + z*h_old[s*H1v+cj];
        h_new[s*H1v+cj] = hv;
        float* ym = &ymax[s*H1v+cj];
        *ym = is_first ? hv : fmaxf(*ym, hv);
    }
}

// sub[bk][j] = relu(concat(ymf, ymb))   [192, 768]
__global__ void sub_build_kernel(const float* __restrict__ ymf, const float* __restrict__ ymb,
                                 float* __restrict__ sub){
    int i = blockIdx.x*256 + threadIdx.x;   // < 192*768
    int r = i / Dv, j = i - r*Dv;
    float v = (j < H1v) ? ymf[r*H1v + j] : ymb[r*H1v + j - H1v];
    sub[i] = fmaxf(v, 0.f);
}

// ---------------------------------------------------------------------------
// Stage-3 bidirectional LSTM step: batch 16, hidden 384. fp32 scalar.
// grid (24, 2), 256 threads. Whh pre-transposed: WT[k*1536 + gj]. xg bf16.
// ---------------------------------------------------------------------------
__global__ void lstm_step_kernel(const float* __restrict__ hof, const float* __restrict__ cof,
                                 const float* __restrict__ hob, const float* __restrict__ cob,
                                 float* __restrict__ hnf, float* __restrict__ cnf,
                                 float* __restrict__ hnb, float* __restrict__ cnb,
                                 const float* __restrict__ WTf, const float* __restrict__ WTb,
                                 const bf16_t* __restrict__ xgf, const bf16_t* __restrict__ xgb,
                                 const float* __restrict__ bhf, const float* __restrict__ bhb,
                                 float* __restrict__ tempmax, int tstep, int is_first)
{
    const int dir = blockIdx.y;
    const float* h_old = dir ? hob : hof;
    const float* c_old = dir ? cob : cof;
    float* h_new = dir ? hnb : hnf;
    float* c_new = dir ? cnb : cnf;
    const float* WT = dir ? WTb : WTf;
    const bf16_t* xg = dir ? xgb : xgf;
    const float* bhh = dir ? bhb : bhf;
    const int lidx = dir ? (Kv-1 - tstep) : tstep;

    int idx = blockIdx.x*256 + threadIdx.x;  // < 16*384
    int row = idx / H1v, j = idx - row*H1v;
    const bf16_t* xrow = &xg[(size_t)(row*Kv + lidx)*G3v];
    float ai = (float)xrow[j]         + bhh[j];
    float af = (float)xrow[H1v+j]     + bhh[H1v+j];
    float ag = (float)xrow[2*H1v+j]   + bhh[2*H1v+j];
    float ao = (float)xrow[3*H1v+j]   + bhh[3*H1v+j];
    const float* hr = &h_old[row*H1v];
    #pragma unroll 4
    for (int k=0;k<H1v;k++){
        float hv = hr[k];
        const float* wr = &WT[(size_t)k*G3v + j];
        ai += hv*wr[0];
        af += hv*wr[H1v];
        ag += hv*wr[2*H1v];
        ao += hv*wr[3*H1v];
    }
    float iv = sigmf(ai), fv = sigmf(af), gv = tanhf(ag), ov = sigmf(ao);
    float c = fv*c_old[idx] + iv*gv;
    float hn = ov*tanhf(c);
    c_new[idx] = c;
    h_new[idx] = hn;
    float* tm = &tempmax[row*Dv + dir*H1v + j];
    *tm = is_first ? hn : fmaxf(*tm, hn);
}

// ---------------------------------------------------------------------------
// Head kernels (fp32, batch = 16)
// ---------------------------------------------------------------------------
__global__ void bn_kernel(const float* __restrict__ x, const float* __restrict__ g,
                          const float* __restrict__ b, float* __restrict__ y, int Dcols){
    int c = blockIdx.x*256 + threadIdx.x;
    if (c >= Dcols) return;
    float mu = 0.f;
    for (int r=0;r<Bv;r++) mu += x[r*Dcols + c];
    mu *= (1.f/Bv);
    float var = 0.f;
    for (int r=0;r<Bv;r++){ float d = x[r*Dcols + c] - mu; var += d*d; }
    var *= (1.f/Bv);
    float sc = g[c]*rsqrtf(var + 1e-5f);
    for (int r=0;r<Bv;r++) y[r*Dcols + c] = sc*(x[r*Dcols + c] - mu) + b[c];
}

__global__ void out_kernel(const float* __restrict__ A, const float* __restrict__ W,
                           const float* __restrict__ b, float* __restrict__ out){
    int bb = blockIdx.x, lane = threadIdx.x;  // 64 threads
    float s = 0.f;
    for (int k=lane;k<Dv;k+=64) s += A[bb*Dv + k]*W[k];
    #pragma unroll
    for (int off=32;off;off>>=1) s += __shfl_down(s,off);
    if (lane==0) out[bb] = 1.f/(1.f + __expf(-(s + b[0])));
}

// ---------------------------------------------------------------------------
// Launch
// ---------------------------------------------------------------------------
extern "C" void kernel_launch(void* const* d_in, const int* in_sizes, int n_in,
                              void* d_out, int out_size, void* d_ws, size_t ws_size,
                              hipStream_t stream) {
    const float* feature = (const float*)d_in[0];
    const int*   src_idx = (const int*)d_in[1];
    const int*   paths   = (const int*)d_in[2];
    const float* emb     = (const float*)d_in[3];
    const float* gWih    = (const float*)d_in[4];
    const float* gWhh    = (const float*)d_in[5];
    const float* gbih    = (const float*)d_in[6];
    const float* gbhh    = (const float*)d_in[7];
    const float* g1fWih  = (const float*)d_in[8];
    const float* g1fWhh  = (const float*)d_in[9];
    const float* g1fbih  = (const float*)d_in[10];
    const float* g1fbhh  = (const float*)d_in[11];
    const float* g1bWih  = (const float*)d_in[12];
    const float* g1bWhh  = (const float*)d_in[13];
    const float* g1bbih  = (const float*)d_in[14];
    const float* g1bbhh  = (const float*)d_in[15];
    const float* lfWih   = (const float*)d_in[16];
    const float* lfWhh   = (const float*)d_in[17];
    const float* lfbih   = (const float*)d_in[18];
    const float* lfbhh   = (const float*)d_in[19];
    const float* lbWih   = (const float*)d_in[20];
    const float* lbWhh   = (const float*)d_in[21];
    const float* lbbih   = (const float*)d_in[22];
    const float* lbbhh   = (const float*)d_in[23];
    const float* treeW   = (const float*)d_in[24];
    const float* treeb   = (const float*)d_in[25];
    const float* bn1g    = (const float*)d_in[26];
    const float* bn1b    = (const float*)d_in[27];
    const float* bn2g    = (const float*)d_in[28];
    const float* bn2b    = (const float*)d_in[29];
    const float* d1W     = (const float*)d_in[30];
    const float* d1b     = (const float*)d_in[31];
    const float* d2W     = (const float*)d_in[32];
    const float* d2b     = (const float*)d_in[33];
    const float* outW    = (const float*)d_in[34];
    const float* outb    = (const float*)d_in[35];
    float* out = (float*)d_out;

    // ---- phased workspace layout (total ~26.6 MB; previous 62.9 MB risked
    // overflowing ws_size and corrupting neighboring allocations) ----
    char* ws = (char*)d_ws;
    size_t off = 0;
    auto alloc = [&](size_t bytes)->char*{
        char* p = ws + off;
        off += (bytes + 255) & ~(size_t)255;
        return p;
    };
    float*  E      = (float*)alloc((size_t)Vv*G1v*4);          // 405,504
    char*   Wreg   = alloc(4718592);                           // time-shared weight scratch
    float*  h_a    = (float*)alloc((size_t)N1v*Dv*4);          // 4,718,592 (later: lWTf/lWTb)
    float*  h_b    = (float*)alloc((size_t)N1v*Dv*4);          // 4,718,592 (later: leafs)
    bf16_t* xg1f   = (bf16_t*)alloc((size_t)N1v*G2v*2);        // 3,538,944
    bf16_t* xg1b   = (bf16_t*)alloc((size_t)N1v*G2v*2);        // 3,538,944
    bf16_t* xg2f   = (bf16_t*)alloc((size_t)BKv*G3v*2);        // 589,824
    bf16_t* xg2b   = (bf16_t*)alloc((size_t)BKv*G3v*2);        // 589,824
    float*  h1f_a  = (float*)alloc((size_t)BKv*H1v*4);
    float*  h1f_b  = (float*)alloc((size_t)BKv*H1v*4);
    float*  h1b_a  = (float*)alloc((size_t)BKv*H1v*4);
    float*  h1b_b  = (float*)alloc((size_t)BKv*H1v*4);
    float*  ymf    = (float*)alloc((size_t)BKv*H1v*4);
    float*  ymb    = (float*)alloc((size_t)BKv*H1v*4);
    float*  sub    = (float*)alloc((size_t)BKv*Dv*4);
    float*  lhf_a  = (float*)alloc((size_t)Bv*H1v*4);
    float*  lhf_b  = (float*)alloc((size_t)Bv*H1v*4);
    float*  lcf_a  = (float*)alloc((size_t)Bv*H1v*4);
    float*  lcf_b  = (float*)alloc((size_t)Bv*H1v*4);
    float*  lhb_a  = (float*)alloc((size_t)Bv*H1v*4);
    float*  lhb_b  = (float*)alloc((size_t)Bv*H1v*4);
    float*  lcb_a  = (float*)alloc((size_t)Bv*H1v*4);
    float*  lcb_b  = (float*)alloc((size_t)Bv*H1v*4);
    float*  tempmax= (float*)alloc((size_t)Bv*Dv*4);
    float*  hb1    = (float*)alloc((size_t)64*Dv*4);           // padded to 64 rows
    float*  hd1    = (float*)alloc((size_t)64*G3v*4);
    float*  hb2    = (float*)alloc((size_t)64*G3v*4);
    float*  hd2    = (float*)alloc((size_t)64*Dv*4);
    (void)ws_size; (void)in_sizes; (void)n_in; (void)out_size;

    // time-shared aliases inside Wreg (stream order makes this safe)
    bf16_t* Whh_bf   = (bf16_t*)Wreg;                          // phase 1 (3,538,944 B)
    bf16_t* treeW_bf = (bf16_t*)Wreg;                          // phase 2
    bf16_t* w1f_bf   = (bf16_t*)(Wreg + 1179648);
    bf16_t* w1b_bf   = (bf16_t*)(Wreg + 1179648 + 1769472);
    bf16_t* u1f_bf   = (bf16_t*)Wreg;                          // phase 3
    bf16_t* u1b_bf   = (bf16_t*)(Wreg + 884736);
    bf16_t* lwf_bf   = (bf16_t*)Wreg;                          // phase 4
    bf16_t* lwb_bf   = (bf16_t*)(Wreg + 2359296);
    bf16_t* d1W_bf   = (bf16_t*)Wreg;                          // phase 5
    bf16_t* d2W_bf   = (bf16_t*)Wreg;                          // phase 6
    // lWT transposes reuse dead h_a region (4,718,592 B = exactly 2x 2,359,296)
    float* lWTf = (float*)h_a;
    float* lWTb = (float*)((char*)h_a + 2359296);

    auto cast = [&](const float* s, bf16_t* d, int n){
        cast_bf16_kernel<<<n/1024, 256, 0, stream>>>(s, d, n/4);
    };

    // ---- phase 1 prep ----
    cast(gWhh, Whh_bf, G1v*Dv);
    ebuild_kernel<<<dim3(Vv, G1v/64), 256, 0, stream>>>(emb, gWih, gbih, E);
    hipMemsetAsync(h_a,  0, (size_t)N1v*Dv*4, stream);
    hipMemsetAsync(h1f_a,0, (size_t)BKv*H1v*4, stream);
    hipMemsetAsync(h1b_a,0, (size_t)BKv*H1v*4, stream);
    hipMemsetAsync(lhf_a,0, (size_t)Bv*H1v*4, stream);
    hipMemsetAsync(lcf_a,0, (size_t)Bv*H1v*4, stream);
    hipMemsetAsync(lhb_a,0, (size_t)Bv*H1v*4, stream);
    hipMemsetAsync(lcb_a,0, (size_t)Bv*H1v*4, stream);
    hipMemsetAsync(hb1,  0, (size_t)64*Dv*4, stream);
    hipMemsetAsync(hb2,  0, (size_t)64*G3v*4, stream);

    // ---- stage 1: token GRU, 24 steps (final h lands in h_a) ----
    float *ho = h_a, *hn = h_b;
    for (int t=0;t<Pv;t++){
        gru_step_kernel<<<dim3(N1v/64, Dv/64), 256, 0, stream>>>(ho, hn, Whh_bf, E, gbhh, paths, src_idx, t);
        float* tmp = ho; ho = hn; hn = tmp;
    }

    // ---- phase 2: leafs + stage-2 input projections ----
    cast(treeW, treeW_bf, Dv*Dv);
    cast(g1fWih, w1f_bf, G2v*Dv);
    cast(g1bWih, w1b_bf, G2v*Dv);
    float* leafs = h_b;  // overwrite stage-1 scratch
    gemm_bt_kernel<float,false><<<dim3(N1v/64, Dv/64), 256, 0, stream>>>(feature, treeW_bf, treeb, ho, leafs, Dv, Dv);
    gemm_bt_kernel<bf16_t,false><<<dim3(N1v/64, G2v/64), 256, 0, stream>>>(leafs, w1f_bf, g1fbih, nullptr, xg1f, G2v, Dv);
    gemm_bt_kernel<bf16_t,false><<<dim3(N1v/64, G2v/64), 256, 0, stream>>>(leafs, w1b_bf, g1bbih, nullptr, xg1b, G2v, Dv);

    // ---- phase 3: stage-2 bidirectional GRU, 8 steps ----
    cast(g1fWhh, u1f_bf, G2v*H1v);
    cast(g1bWhh, u1b_bf, G2v*H1v);
    float *g1of=h1f_a, *g1nf=h1f_b, *g1ob=h1b_a, *g1nb=h1b_b;
    for (int t=0;t<Lv;t++){
        gru1_step_kernel<<<dim3(BKv/64, H1v/64, 2), 256, 0, stream>>>(
            g1of, g1ob, g1nf, g1nb, u1f_bf, u1b_bf, xg1f, xg1b, g1fbhh, g1bbhh, ymf, ymb, t, t==0?1:0);
        float* tmp;
        tmp=g1of; g1of=g1nf; g1nf=tmp;
        tmp=g1ob; g1ob=g1nb; g1nb=tmp;
    }
    sub_build_kernel<<<(BKv*Dv)/256, 256, 0, stream>>>(ymf, ymb, sub);

    // ---- phase 4: stage-3 input projections + LSTM ----
    cast(lfWih, lwf_bf, G3v*Dv);
    cast(lbWih, lwb_bf, G3v*Dv);
    gemm_bt_kernel<bf16_t,false><<<dim3(BKv/64, G3v/64), 256, 0, stream>>>(sub, lwf_bf, lfbih, nullptr, xg2f, G3v, Dv);
    gemm_bt_kernel<bf16_t,false><<<dim3(BKv/64, G3v/64), 256, 0, stream>>>(sub, lwb_bf, lbbih, nullptr, xg2b, G3v, Dv);
    transpose_kernel<<<(G3v*H1v+255)/256, 256, 0, stream>>>(lfWhh, lWTf, G3v, H1v);  // h_a dead -> reuse
    transpose_kernel<<<(G3v*H1v+255)/256, 256, 0, stream>>>(lbWhh, lWTb, G3v, H1v);

    float *lho=lhf_a,*lhn=lhf_b,*lco=lcf_a,*lcn=lcf_b;
    float *lhob=lhb_a,*lhnb=lhb_b,*lcob=lcb_a,*lcnb=lcb_b;
    for (int t=0;t<Kv;t++){
        lstm_step_kernel<<<dim3((Bv*H1v)/256, 2), 256, 0, stream>>>(
            lho, lco, lhob, lcob, lhn, lcn, lhnb, lcnb,
            lWTf, lWTb, xg2f, xg2b, lfbhh, lbbhh, tempmax, t, t==0?1:0);
        float* tmp;
        tmp=lho; lho=lhn; lhn=tmp;  tmp=lco; lco=lcn; lcn=tmp;
        tmp=lhob; lhob=lhnb; lhnb=tmp;  tmp=lcob; lcob=lcnb; lcnb=tmp;
    }

    // ---- head (M padded to 64; pad rows of hb1/hb2 zeroed above) ----
    bn_kernel<<<(Dv+255)/256, 256, 0, stream>>>(tempmax, bn1g, bn1b, hb1, Dv);
    cast(d1W, d1W_bf, G3v*Dv);
    gemm_bt_kernel<float,true><<<dim3(1, G3v/64), 256, 0, stream>>>(hb1, d1W_bf, d1b, nullptr, hd1, G3v, Dv);
    bn_kernel<<<(G3v+255)/256, 256, 0, stream>>>(hd1, bn2g, bn2b, hb2, G3v);
    cast(d2W, d2W_bf, Dv*G3v);
    gemm_bt_kernel<float,true><<<dim3(1, Dv/64), 256, 0, stream>>>(hb2, d2W_bf, d2b, nullptr, hd2, Dv, G3v);
    out_kernel<<<Bv, 64, 0, stream>>>(hd2, outW, outb, out);
}

// Round 3
// 1638.573 us; speedup vs baseline: 1.1455x; 1.1455x over previous
//
#include <hip/hip_runtime.h>

// ---------------------------------------------------------------------------
// Dims (fixed by the reference)
// ---------------------------------------------------------------------------
#define Bv 16
#define Kv 12
#define Lv 8
#define Pv 24
#define Dv 768
#define H1v 384
#define Vv 44
#define KLv 96          // K*L
#define N1v 1536        // B*K*L
#define BKv 192         // B*K
#define G1v 2304        // 3*D
#define G2v 1152        // 3*H1
#define G3v 1536        // 4*H1

typedef __bf16 bf16_t;
typedef __attribute__((ext_vector_type(8))) __bf16 bf16x8;
typedef __attribute__((ext_vector_type(4))) __bf16 bf16x4;
typedef __attribute__((ext_vector_type(4))) float f32x4;

__device__ __forceinline__ float sigmf(float x){ return 1.0f/(1.0f + __expf(-x)); }
__device__ __forceinline__ float tanhft(float x){ float e = __expf(2.f*x); return 1.f - 2.f/(e+1.f); }

// async global->LDS, 16B per lane. LDS dest must be wave-uniform base + lane*16.
__device__ __forceinline__ void gld_lds16(const bf16_t* g, bf16_t* l){
    __builtin_amdgcn_global_load_lds(
        (const __attribute__((address_space(1))) void*)g,
        (__attribute__((address_space(3))) void*)l, 16, 0, 0);
}

// group barrier: monotonic counter, agent scope. All member blocks co-resident
// (grid << residency capacity). Release: entry __syncthreads drains stores to
// L2, thread0's __threadfence writes back the XCD L2. Acquire: fence after spin.
__device__ __forceinline__ void group_barrier(int* bar, int target){
    __syncthreads();
    if (threadIdx.x == 0){
        __threadfence();
        __hip_atomic_fetch_add(bar, 1, __ATOMIC_RELAXED, __HIP_MEMORY_SCOPE_AGENT);
        while (__hip_atomic_load(bar, __ATOMIC_RELAXED, __HIP_MEMORY_SCOPE_AGENT) < target)
            __builtin_amdgcn_s_sleep(2);
        __threadfence();
    }
    __syncthreads();
}

// ---------------------------------------------------------------------------
// Prep
// ---------------------------------------------------------------------------
__global__ void cast_bf16_kernel(const float* __restrict__ src, bf16_t* __restrict__ dst, int n4){
    int i = blockIdx.x*256 + threadIdx.x;
    if (i < n4){
        float4 f = reinterpret_cast<const float4*>(src)[i];
        bf16_t o[4] = {(bf16_t)f.x,(bf16_t)f.y,(bf16_t)f.z,(bf16_t)f.w};
        reinterpret_cast<ushort4*>(dst)[i] = *reinterpret_cast<ushort4*>(o);
    }
}

// ---------------------------------------------------------------------------
// Generic BT-GEMM: C[M,N] = A[M,K] @ B[N,K]^T (+bias[N]) (+add[M,N])
// ---------------------------------------------------------------------------
template<typename CT, bool RELU>
__launch_bounds__(256, 4)
__global__ void gemm_bt_kernel(const float* __restrict__ A, const bf16_t* __restrict__ B,
                               const float* __restrict__ bias, const float* __restrict__ add,
                               CT* __restrict__ C, int N, int K)
{
    __shared__ bf16_t As[64][40];
    __shared__ bf16_t Bs[64][40];
    const int tid = threadIdx.x;
    const int m0 = blockIdx.x*64, n0 = blockIdx.y*64;
    const int w = tid>>6, lane = tid&63;
    const int wm = w&1, wn = w>>1;
    const int arow = tid>>2, ac8 = (tid&3)*8;
    f32x4 acc[2][2];
    #pragma unroll
    for (int i=0;i<2;i++)
        #pragma unroll
        for (int j=0;j<2;j++) acc[i][j] = f32x4{0.f,0.f,0.f,0.f};

    for (int kk=0; kk<K; kk+=32){
        {
            const float4 f0 = *reinterpret_cast<const float4*>(&A[(size_t)(m0+arow)*K + kk + ac8]);
            const float4 f1 = *reinterpret_cast<const float4*>(&A[(size_t)(m0+arow)*K + kk + ac8 + 4]);
            bf16x8 v;
            v[0]=(bf16_t)f0.x; v[1]=(bf16_t)f0.y; v[2]=(bf16_t)f0.z; v[3]=(bf16_t)f0.w;
            v[4]=(bf16_t)f1.x; v[5]=(bf16_t)f1.y; v[6]=(bf16_t)f1.z; v[7]=(bf16_t)f1.w;
            *reinterpret_cast<bf16x8*>(&As[arow][ac8]) = v;
        }
        *reinterpret_cast<uint4*>(&Bs[arow][ac8]) =
            *reinterpret_cast<const uint4*>(&B[(size_t)(n0+arow)*K + kk + ac8]);
        __syncthreads();
        const int fr = lane&15, fk = (lane>>4)*8;
        bf16x8 a0 = *reinterpret_cast<const bf16x8*>(&As[wm*32+fr][fk]);
        bf16x8 a1 = *reinterpret_cast<const bf16x8*>(&As[wm*32+16+fr][fk]);
        bf16x8 b0 = *reinterpret_cast<const bf16x8*>(&Bs[wn*32+fr][fk]);
        bf16x8 b1 = *reinterpret_cast<const bf16x8*>(&Bs[wn*32+16+fr][fk]);
        acc[0][0] = __builtin_amdgcn_mfma_f32_16x16x32_bf16(a0,b0,acc[0][0],0,0,0);
        acc[0][1] = __builtin_amdgcn_mfma_f32_16x16x32_bf16(a0,b1,acc[0][1],0,0,0);
        acc[1][0] = __builtin_amdgcn_mfma_f32_16x16x32_bf16(a1,b0,acc[1][0],0,0,0);
        acc[1][1] = __builtin_amdgcn_mfma_f32_16x16x32_bf16(a1,b1,acc[1][1],0,0,0);
        __syncthreads();
    }
    const int fj = lane&15, fi4 = (lane>>4)*4;
    #pragma unroll
    for (int mt=0;mt<2;mt++)
        #pragma unroll
        for (int nt=0;nt<2;nt++){
            int gr = m0 + wm*32 + mt*16 + fi4;
            int gc = n0 + wn*32 + nt*16 + fj;
            float bv = bias ? bias[gc] : 0.f;
            #pragma unroll
            for (int r=0;r<4;r++){
                float v = acc[mt][nt][r] + bv;
                if (add) v += add[(size_t)(gr+r)*N + gc];
                if (RELU) v = fmaxf(v, 0.f);
                C[(size_t)(gr+r)*N + gc] = (CT)v;
            }
        }
}

// ---------------------------------------------------------------------------
// Stage-1 persistent token-GRU: batch 1536, hidden 768, 24 steps.
// grid (24,12); block = 64 rows x 64 h-cols. Gates entirely in registers:
// wave wn covers cols [wn*32, wn*32+32), fragments nt = g*2+cs so r/z/n for a
// given output element share lane+reg. Double-buffered LDS; B via DMA.
// Row-group barrier: block (bx,by) only needs h rows written by (bx,*).
// ---------------------------------------------------------------------------
__launch_bounds__(256, 2)
__global__ void gru_seq_kernel(float* __restrict__ h_a, float* __restrict__ h_b,
                               const bf16_t* __restrict__ Whh,   // [2304,768]
                               const float* __restrict__ E,      // [64,2304] (rows 0..43 used)
                               const float* __restrict__ bhh,
                               const int* __restrict__ paths,
                               const int* __restrict__ src_idx,
                               int* __restrict__ bars)
{
    __shared__ bf16_t As[2][64][40];
    __shared__ bf16_t Bs[2][192][32];
    __shared__ int tok_s[64];

    const int tid = threadIdx.x;
    const int s0 = blockIdx.x*64, c0 = blockIdx.y*64;
    const int lane = tid&63, w = tid>>6;
    const int wm = w&1, wn = w>>1;
    const int arow = tid>>2, ac8 = (tid&3)*8;
    const int fr = lane&15, fk = (lane>>4)*8;
    const int ec0 = c0 + wn*32 + fr;                // epilogue col (cs=0)
    const int er0 = s0 + wm*32 + (lane>>4)*4;       // epilogue row base
    int* bar = bars + blockIdx.x;

    float bh_r[2], bh_z[2], bh_n[2];
    #pragma unroll
    for (int cs=0; cs<2; cs++){
        int cj = ec0 + cs*16;
        bh_r[cs]=bhh[cj]; bh_z[cs]=bhh[Dv+cj]; bh_n[cs]=bhh[2*Dv+cj];
    }

    for (int t=0; t<Pv; ++t){
        const float* h_old = (t&1) ? h_b : h_a;
        float*       h_new = (t&1) ? h_a : h_b;
        if (tid < 64){
            int s = s0 + tid;
            int b = s / KLv;
            int rest = s - b*KLv;
            tok_s[tid] = paths[(src_idx[b]*KLv + rest)*Pv + t];
        }
        f32x4 acc[2][6];
        #pragma unroll
        for (int i=0;i<2;i++)
            #pragma unroll
            for (int j=0;j<6;j++) acc[i][j] = f32x4{0.f,0.f,0.f,0.f};

        // prologue: kk=0 into buf 0
        {
            const float4 f0 = *(const float4*)&h_old[(size_t)(s0+arow)*Dv + ac8];
            const float4 f1 = *(const float4*)&h_old[(size_t)(s0+arow)*Dv + ac8 + 4];
            #pragma unroll
            for (int i=0;i<3;i++){
                int idx = tid + 256*i;
                int row = idx>>2, q = idx&3;
                int grow = (row>>6)*Dv + c0 + (row&63);
                gld_lds16(&Whh[(size_t)grow*Dv + q*8], &Bs[0][0][0] + idx*8);
            }
            bf16x8 v;
            v[0]=(bf16_t)f0.x; v[1]=(bf16_t)f0.y; v[2]=(bf16_t)f0.z; v[3]=(bf16_t)f0.w;
            v[4]=(bf16_t)f1.x; v[5]=(bf16_t)f1.y; v[6]=(bf16_t)f1.z; v[7]=(bf16_t)f1.w;
            *(bf16x8*)&As[0][arow][ac8] = v;
        }
        int cur = 0;
        for (int ki=0; ki<24; ++ki){
            __syncthreads();     // drains DMA vmcnt: buf[cur] complete
            float4 f0, f1;
            if (ki < 23){
                int kk = (ki+1)*32;
                f0 = *(const float4*)&h_old[(size_t)(s0+arow)*Dv + kk + ac8];
                f1 = *(const float4*)&h_old[(size_t)(s0+arow)*Dv + kk + ac8 + 4];
                #pragma unroll
                for (int i=0;i<3;i++){
                    int idx = tid + 256*i;
                    int row = idx>>2, q = idx&3;
                    int grow = (row>>6)*Dv + c0 + (row&63);
                    gld_lds16(&Whh[(size_t)grow*Dv + kk + q*8], &Bs[cur^1][0][0] + idx*8);
                }
            }
            const bf16_t* ab = &As[cur][0][0];
            const bf16_t* bb = &Bs[cur][0][0];
            bf16x8 afr0 = *(const bf16x8*)(ab + (wm*32+fr)*40 + fk);
            bf16x8 afr1 = *(const bf16x8*)(ab + (wm*32+16+fr)*40 + fk);
            #pragma unroll
            for (int g=0; g<3; ++g)
                #pragma unroll
                for (int cs=0; cs<2; ++cs){
                    bf16x8 bfr = *(const bf16x8*)(bb + (g*64 + wn*32 + cs*16 + fr)*32 + fk);
                    int nt = g*2+cs;
                    acc[0][nt] = __builtin_amdgcn_mfma_f32_16x16x32_bf16(afr0, bfr, acc[0][nt],0,0,0);
                    acc[1][nt] = __builtin_amdgcn_mfma_f32_16x16x32_bf16(afr1, bfr, acc[1][nt],0,0,0);
                }
            if (ki < 23){
                bf16x8 v;
                v[0]=(bf16_t)f0.x; v[1]=(bf16_t)f0.y; v[2]=(bf16_t)f0.z; v[3]=(bf16_t)f0.w;
                v[4]=(bf16_t)f1.x; v[5]=(bf16_t)f1.y; v[6]=(bf16_t)f1.z; v[7]=(bf16_t)f1.w;
                *(bf16x8*)&As[cur^1][arow][ac8] = v;
            }
            cur ^= 1;
        }
        // epilogue: gates in registers
        #pragma unroll
        for (int mt=0; mt<2; ++mt)
            #pragma unroll
            for (int r4=0; r4<4; ++r4){
                int s = er0 + mt*16 + r4;
                int tok = tok_s[s - s0];
                const float* Erow = E + (size_t)tok*G1v;
                #pragma unroll
                for (int cs=0; cs<2; ++cs){
                    int cj = ec0 + cs*16;
                    float gr  = Erow[cj]      + acc[mt][cs][r4]   + bh_r[cs];
                    float gz  = Erow[Dv+cj]   + acc[mt][2+cs][r4] + bh_z[cs];
                    float gnx = Erow[2*Dv+cj];
                    float ghn = acc[mt][4+cs][r4] + bh_n[cs];
                    float r = sigmf(gr), z = sigmf(gz);
                    float n = tanhft(gnx + r*ghn);
                    float hp = h_old[(size_t)s*Dv + cj];
                    h_new[(size_t)s*Dv + cj] = (1.f - z)*n + z*hp;
                }
            }
        if (t < Pv-1) group_barrier(bar, 12*(t+1));
    }
}

// ---------------------------------------------------------------------------
// Stage-2 persistent bidirectional GRU: batch 192, hidden 384, 8 steps.
// grid (6,12,2); block = 32 rows x 32 h-cols; running max + relu-concat in regs.
// ---------------------------------------------------------------------------
__launch_bounds__(256, 2)
__global__ void gru1_seq_kernel(float* __restrict__ hf_a, float* __restrict__ hf_b,
                                float* __restrict__ hb_a, float* __restrict__ hb_b,
                                const bf16_t* __restrict__ Whf, const bf16_t* __restrict__ Whb,
                                const bf16_t* __restrict__ xgf, const bf16_t* __restrict__ xgb,
                                const float* __restrict__ bhf, const float* __restrict__ bhb,
                                float* __restrict__ sub, int* __restrict__ bars)
{
    __shared__ bf16_t As[2][32][40];
    __shared__ bf16_t Bs[2][96][32];
    const int tid = threadIdx.x;
    const int dir = blockIdx.z;
    float* bufA = dir ? hb_a : hf_a;
    float* bufB = dir ? hb_b : hf_b;
    const bf16_t* Whh = dir ? Whb : Whf;
    const bf16_t* xg  = dir ? xgb : xgf;
    const float* bhh  = dir ? bhb : bhf;
    int* bar = bars + dir*6 + blockIdx.x;

    const int s0 = blockIdx.x*32, c0 = blockIdx.y*32;
    const int lane = tid&63, w = tid>>6;
    const int wm = w&1, wn = w>>1;
    const int arow = tid>>3, ac4 = (tid&7)*4;
    const int fr = lane&15, fk = (lane>>4)*8;
    const int ec = c0 + wn*16 + fr;
    const int er0 = s0 + wm*16 + (lane>>4)*4;
    const float bh_r = bhh[ec], bh_z = bhh[H1v+ec], bh_n = bhh[2*H1v+ec];
    float ym[4];

    for (int t=0; t<Lv; ++t){
        const float* h_old = (t&1) ? bufB : bufA;
        float*       h_new = (t&1) ? bufA : bufB;
        const int lidx = dir ? (Lv-1-t) : t;
        f32x4 acc[3];
        acc[0]=acc[1]=acc[2]=f32x4{0.f,0.f,0.f,0.f};
        {
            const float4 f = *(const float4*)&h_old[(size_t)(s0+arow)*H1v + ac4];
            #pragma unroll
            for (int i=0;i<2;i++){
                int idx = tid + 256*i;
                if (idx < 384){
                    int row = idx>>2, q = idx&3;
                    int grow = (row>>5)*H1v + c0 + (row&31);
                    gld_lds16(&Whh[(size_t)grow*H1v + q*8], &Bs[0][0][0] + idx*8);
                }
            }
            bf16x4 v; v[0]=(bf16_t)f.x; v[1]=(bf16_t)f.y; v[2]=(bf16_t)f.z; v[3]=(bf16_t)f.w;
            *(bf16x4*)&As[0][arow][ac4] = v;
        }
        int cur = 0;
        for (int ki=0; ki<12; ++ki){
            __syncthreads();
            float4 f;
            if (ki < 11){
                int kk = (ki+1)*32;
                f = *(const float4*)&h_old[(size_t)(s0+arow)*H1v + kk + ac4];
                #pragma unroll
                for (int i=0;i<2;i++){
                    int idx = tid + 256*i;
                    if (idx < 384){
                        int row = idx>>2, q = idx&3;
                        int grow = (row>>5)*H1v + c0 + (row&31);
                        gld_lds16(&Whh[(size_t)grow*H1v + kk + q*8], &Bs[cur^1][0][0] + idx*8);
                    }
                }
            }
            const bf16_t* ab = &As[cur][0][0];
            const bf16_t* bb = &Bs[cur][0][0];
            bf16x8 afr = *(const bf16x8*)(ab + (wm*16+fr)*40 + fk);
            #pragma unroll
            for (int g=0; g<3; ++g){
                bf16x8 bfr = *(const bf16x8*)(bb + (g*32 + wn*16 + fr)*32 + fk);
                acc[g] = __builtin_amdgcn_mfma_f32_16x16x32_bf16(afr, bfr, acc[g],0,0,0);
            }
            if (ki < 11){
                bf16x4 v; v[0]=(bf16_t)f.x; v[1]=(bf16_t)f.y; v[2]=(bf16_t)f.z; v[3]=(bf16_t)f.w;
                *(bf16x4*)&As[cur^1][arow][ac4] = v;
            }
            cur ^= 1;
        }
        #pragma unroll
        for (int r4=0;r4<4;r4++){
            int s = er0 + r4;
            const bf16_t* xrow = xg + ((size_t)s*Lv + lidx)*G2v;
            float gr  = (float)xrow[ec]       + acc[0][r4] + bh_r;
            float gz  = (float)xrow[H1v+ec]   + acc[1][r4] + bh_z;
            float gnx = (float)xrow[2*H1v+ec];
            float ghn = acc[2][r4] + bh_n;
            float r = sigmf(gr), z = sigmf(gz);
            float n = tanhft(gnx + r*ghn);
            float hp = h_old[(size_t)s*H1v + ec];
            float hv = (1.f - z)*n + z*hp;
            h_new[(size_t)s*H1v + ec] = hv;
            ym[r4] = (t==0) ? hv : fmaxf(ym[r4], hv);
        }
        if (t < Lv-1) group_barrier(bar, 12*(t+1));
    }
    #pragma unroll
    for (int r4=0;r4<4;r4++){
        int s = er0 + r4;
        sub[(size_t)s*Dv + dir*H1v + ec] = fmaxf(ym[r4], 0.f);
    }
}

// ---------------------------------------------------------------------------
// Stage-3 persistent bidirectional LSTM: batch 16, hidden 384, 12 steps.
// grid (6,2); block = 64 h-cols x all 16 rows x 4 gates. MFMA M=16; c-state
// and running max in registers.
// ---------------------------------------------------------------------------
__launch_bounds__(256, 2)
__global__ void lstm_seq_kernel(float* __restrict__ hf_a, float* __restrict__ hf_b,
                                float* __restrict__ hb_a, float* __restrict__ hb_b,
                                const bf16_t* __restrict__ Wf, const bf16_t* __restrict__ Wb, // [1536,384]
                                const bf16_t* __restrict__ xgf, const bf16_t* __restrict__ xgb,
                                const float* __restrict__ bhf, const float* __restrict__ bhb,
                                float* __restrict__ tempmax, int* __restrict__ bars)
{
    __shared__ bf16_t As[2][16][40];
    __shared__ bf16_t Bs[2][256][32];
    const int tid = threadIdx.x;
    const int dir = blockIdx.y;
    float* bufA = dir ? hb_a : hf_a;
    float* bufB = dir ? hb_b : hf_b;
    const bf16_t* Whh = dir ? Wb : Wf;
    const bf16_t* xg  = dir ? xgb : xgf;
    const float* bhh  = dir ? bhb : bhf;
    int* bar = bars + dir;
    const int c0 = blockIdx.x*64;
    const int lane = tid&63, w = tid>>6;
    const int fr = lane&15, fk = (lane>>4)*8;
    const int hcol = c0 + w*16 + fr;
    const int r0 = (lane>>4)*4;
    float bh[4];
    #pragma unroll
    for (int g=0; g<4; ++g) bh[g] = bhh[g*H1v + hcol];
    float cst[4] = {0.f,0.f,0.f,0.f};
    float tm[4];

    for (int t=0; t<Kv; ++t){
        const float* h_old = (t&1) ? bufB : bufA;
        float*       h_new = (t&1) ? bufA : bufB;
        const int lidx = dir ? (Kv-1-t) : t;
        f32x4 acc[4];
        acc[0]=acc[1]=acc[2]=acc[3]=f32x4{0.f,0.f,0.f,0.f};
        {
            #pragma unroll
            for (int i=0;i<4;i++){
                int idx = tid + 256*i;
                int row = idx>>2, q = idx&3;
                int grow = (row>>6)*H1v + c0 + (row&63);
                gld_lds16(&Whh[(size_t)grow*H1v + q*8], &Bs[0][0][0] + idx*8);
            }
            if (tid < 128){
                int arow = tid>>3, ac4 = (tid&7)*4;
                const float4 f = *(const float4*)&h_old[(size_t)arow*H1v + ac4];
                bf16x4 v; v[0]=(bf16_t)f.x; v[1]=(bf16_t)f.y; v[2]=(bf16_t)f.z; v[3]=(bf16_t)f.w;
                *(bf16x4*)&As[0][arow][ac4] = v;
            }
        }
        int cur = 0;
        for (int ki=0; ki<12; ++ki){
            __syncthreads();
            float4 f;
            int arow = tid>>3, ac4 = (tid&7)*4;
            if (ki < 11){
                int kk = (ki+1)*32;
                #pragma unroll
                for (int i=0;i<4;i++){
                    int idx = tid + 256*i;
                    int row = idx>>2, q = idx&3;
                    int grow = (row>>6)*H1v + c0 + (row&63);
                    gld_lds16(&Whh[(size_t)grow*H1v + kk + q*8], &Bs[cur^1][0][0] + idx*8);
                }
                if (tid < 128)
                    f = *(const float4*)&h_old[(size_t)arow*H1v + kk + ac4];
            }
            const bf16_t* ab = &As[cur][0][0];
            const bf16_t* bb = &Bs[cur][0][0];
            bf16x8 afr = *(const bf16x8*)(ab + fr*40 + fk);
            #pragma unroll
            for (int g=0; g<4; ++g){
                bf16x8 bfr = *(const bf16x8*)(bb + (g*64 + w*16 + fr)*32 + fk);
                acc[g] = __builtin_amdgcn_mfma_f32_16x16x32_bf16(afr, bfr, acc[g],0,0,0);
            }
            if (ki < 11 && tid < 128){
                bf16x4 v; v[0]=(bf16_t)f.x; v[1]=(bf16_t)f.y; v[2]=(bf16_t)f.z; v[3]=(bf16_t)f.w;
                *(bf16x4*)&As[cur^1][arow][ac4] = v;
            }
            cur ^= 1;
        }
        #pragma unroll
        for (int r4=0;r4<4;r4++){
            int r = r0 + r4;
            const bf16_t* xrow = xg + ((size_t)r*Kv + lidx)*G3v;
            float ai = (float)xrow[hcol]        + acc[0][r4] + bh[0];
            float af = (float)xrow[H1v+hcol]    + acc[1][r4] + bh[1];
            float ag = (float)xrow[2*H1v+hcol]  + acc[2][r4] + bh[2];
            float ao = (float)xrow[3*H1v+hcol]  + acc[3][r4] + bh[3];
            float iv = sigmf(ai), fv = sigmf(af), gv = tanhft(ag), ov = sigmf(ao);
            cst[r4] = fv*cst[r4] + iv*gv;
            float hn = ov*tanhft(cst[r4]);
            h_new[(size_t)r*H1v + hcol] = hn;
            tm[r4] = (t==0) ? hn : fmaxf(tm[r4], hn);
        }
        if (t < Kv-1) group_barrier(bar, 6*(t+1));
    }
    #pragma unroll
    for (int r4=0;r4<4;r4++)
        tempmax[(size_t)(r0+r4)*Dv + dir*H1v + hcol] = tm[r4];
}

// ---------------------------------------------------------------------------
// Head kernels (fp32, batch = 16)
// ---------------------------------------------------------------------------
__global__ void bn_kernel(const float* __restrict__ x, const float* __restrict__ g,
                          const float* __restrict__ b, float* __restrict__ y, int Dcols){
    int c = blockIdx.x*256 + threadIdx.x;
    if (c >= Dcols) return;
    float mu = 0.f;
    for (int r=0;r<Bv;r++) mu += x[r*Dcols + c];
    mu *= (1.f/Bv);
    float var = 0.f;
    for (int r=0;r<Bv;r++){ float d = x[r*Dcols + c] - mu; var += d*d; }
    var *= (1.f/Bv);
    float sc = g[c]*rsqrtf(var + 1e-5f);
    for (int r=0;r<Bv;r++) y[r*Dcols + c] = sc*(x[r*Dcols + c] - mu) + b[c];
}

__global__ void out_kernel(const float* __restrict__ A, const float* __restrict__ W,
                           const float* __restrict__ b, float* __restrict__ out){
    int bb = blockIdx.x, lane = threadIdx.x;  // 64 threads
    float s = 0.f;
    for (int k=lane;k<Dv;k+=64) s += A[bb*Dv + k]*W[k];
    #pragma unroll
    for (int off=32;off;off>>=1) s += __shfl_down(s,off);
    if (lane==0) out[bb] = 1.f/(1.f + __expf(-(s + b[0])));
}

// ---------------------------------------------------------------------------
// Launch
// ---------------------------------------------------------------------------
extern "C" void kernel_launch(void* const* d_in, const int* in_sizes, int n_in,
                              void* d_out, int out_size, void* d_ws, size_t ws_size,
                              hipStream_t stream) {
    const float* feature = (const float*)d_in[0];
    const int*   src_idx = (const int*)d_in[1];
    const int*   paths   = (const int*)d_in[2];
    const float* emb     = (const float*)d_in[3];
    const float* gWih    = (const float*)d_in[4];
    const float* gWhh    = (const float*)d_in[5];
    const float* gbih    = (const float*)d_in[6];
    const float* gbhh    = (const float*)d_in[7];
    const float* g1fWih  = (const float*)d_in[8];
    const float* g1fWhh  = (const float*)d_in[9];
    const float* g1fbih  = (const float*)d_in[10];
    const float* g1fbhh  = (const float*)d_in[11];
    const float* g1bWih  = (const float*)d_in[12];
    const float* g1bWhh  = (const float*)d_in[13];
    const float* g1bbih  = (const float*)d_in[14];
    const float* g1bbhh  = (const float*)d_in[15];
    const float* lfWih   = (const float*)d_in[16];
    const float* lfWhh   = (const float*)d_in[17];
    const float* lfbih   = (const float*)d_in[18];
    const float* lfbhh   = (const float*)d_in[19];
    const float* lbWih   = (const float*)d_in[20];
    const float* lbWhh   = (const float*)d_in[21];
    const float* lbbih   = (const float*)d_in[22];
    const float* lbbhh   = (const float*)d_in[23];
    const float* treeW   = (const float*)d_in[24];
    const float* treeb   = (const float*)d_in[25];
    const float* bn1g    = (const float*)d_in[26];
    const float* bn1b    = (const float*)d_in[27];
    const float* bn2g    = (const float*)d_in[28];
    const float* bn2b    = (const float*)d_in[29];
    const float* d1W     = (const float*)d_in[30];
    const float* d1b     = (const float*)d_in[31];
    const float* d2W     = (const float*)d_in[32];
    const float* d2b     = (const float*)d_in[33];
    const float* outW    = (const float*)d_in[34];
    const float* outb    = (const float*)d_in[35];
    float* out = (float*)d_out;

    // ---- workspace (~26.5 MB; same footprint class that passed in r2) ----
    char* ws = (char*)d_ws;
    size_t off = 0;
    auto alloc = [&](size_t bytes)->char*{
        char* p = ws + off;
        off += (bytes + 255) & ~(size_t)255;
        return p;
    };
    float*  E      = (float*)alloc((size_t)64*G1v*4);          // padded rows
    char*   Wreg   = alloc(4718592);                           // time-shared weight scratch
    float*  emb_pad= (float*)alloc((size_t)64*Dv*4);
    float*  h_a    = (float*)alloc((size_t)N1v*Dv*4);
    float*  h_b    = (float*)alloc((size_t)N1v*Dv*4);          // later: leafs
    bf16_t* xg1f   = (bf16_t*)alloc((size_t)N1v*G2v*2);
    bf16_t* xg1b   = (bf16_t*)alloc((size_t)N1v*G2v*2);
    bf16_t* xg2f   = (bf16_t*)alloc((size_t)BKv*G3v*2);
    bf16_t* xg2b   = (bf16_t*)alloc((size_t)BKv*G3v*2);
    float*  h1f_a  = (float*)alloc((size_t)BKv*H1v*4);
    float*  h1f_b  = (float*)alloc((size_t)BKv*H1v*4);
    float*  h1b_a  = (float*)alloc((size_t)BKv*H1v*4);
    float*  h1b_b  = (float*)alloc((size_t)BKv*H1v*4);
    float*  sub    = (float*)alloc((size_t)BKv*Dv*4);
    float*  lhf_a  = (float*)alloc((size_t)Bv*H1v*4);
    float*  lhf_b  = (float*)alloc((size_t)Bv*H1v*4);
    float*  lhb_a  = (float*)alloc((size_t)Bv*H1v*4);
    float*  lhb_b  = (float*)alloc((size_t)Bv*H1v*4);
    float*  tempmax= (float*)alloc((size_t)Bv*Dv*4);
    float*  hb1    = (float*)alloc((size_t)64*Dv*4);
    float*  hd1    = (float*)alloc((size_t)64*G3v*4);
    float*  hb2    = (float*)alloc((size_t)64*G3v*4);
    float*  hd2    = (float*)alloc((size_t)64*Dv*4);
    int*    bars   = (int*)alloc(256);
    int* bars1 = bars;        // 24 groups (stage 1)
    int* bars2 = bars + 24;   // 12 groups (stage 2)
    int* bars3 = bars + 40;   // 2 groups  (lstm)
    (void)ws_size; (void)in_sizes; (void)n_in; (void)out_size;

    // time-shared aliases inside Wreg (stream order makes each phase safe)
    bf16_t* gWih_bf  = (bf16_t*)Wreg;                          // phase 0
    bf16_t* Whh_bf   = (bf16_t*)Wreg;                          // phase 1
    bf16_t* treeW_bf = (bf16_t*)Wreg;                          // phase 2
    bf16_t* w1f_bf   = (bf16_t*)(Wreg + 1179648);
    bf16_t* w1b_bf   = (bf16_t*)(Wreg + 2949120);
    bf16_t* u1f_bf   = (bf16_t*)Wreg;                          // phase 3
    bf16_t* u1b_bf   = (bf16_t*)(Wreg + 884736);
    bf16_t* lwf_bf   = (bf16_t*)Wreg;                          // phase 4
    bf16_t* lwb_bf   = (bf16_t*)(Wreg + 2359296);
    bf16_t* lWf_bf   = (bf16_t*)Wreg;                          // phase 5
    bf16_t* lWb_bf   = (bf16_t*)(Wreg + 1179648);
    bf16_t* d1W_bf   = (bf16_t*)Wreg;                          // phase 6
    bf16_t* d2W_bf   = (bf16_t*)Wreg;                          // phase 7

    auto cast = [&](const float* s, bf16_t* d, int n){
        cast_bf16_kernel<<<n/1024, 256, 0, stream>>>(s, d, n/4);
    };

    // ---- init (ws is re-poisoned before every call) ----
    hipMemsetAsync(bars, 0, 256, stream);
    hipMemsetAsync(emb_pad, 0, (size_t)64*Dv*4, stream);
    hipMemsetAsync(h_a,   0, (size_t)N1v*Dv*4, stream);
    hipMemsetAsync(h1f_a, 0, (size_t)BKv*H1v*4, stream);
    hipMemsetAsync(h1b_a, 0, (size_t)BKv*H1v*4, stream);
    hipMemsetAsync(lhf_a, 0, (size_t)Bv*H1v*4, stream);
    hipMemsetAsync(lhb_a, 0, (size_t)Bv*H1v*4, stream);
    hipMemsetAsync(hb1,   0, (size_t)64*Dv*4, stream);
    hipMemsetAsync(hb2,   0, (size_t)64*G3v*4, stream);
    hipMemcpyAsync(emb_pad, emb, (size_t)Vv*Dv*4, hipMemcpyDeviceToDevice, stream);

    // ---- E = emb @ gWih^T + gbih  (padded to 64 rows) ----
    cast(gWih, gWih_bf, G1v*Dv);
    gemm_bt_kernel<float,false><<<dim3(1, G1v/64), 256, 0, stream>>>(emb_pad, gWih_bf, gbih, nullptr, E, G1v, Dv);

    // ---- stage 1: persistent token GRU (final h lands in h_a) ----
    cast(gWhh, Whh_bf, G1v*Dv);
    gru_seq_kernel<<<dim3(N1v/64, Dv/64), 256, 0, stream>>>(h_a, h_b, Whh_bf, E, gbhh, paths, src_idx, bars1);

    // ---- leafs + stage-2 input projections ----
    cast(treeW, treeW_bf, Dv*Dv);
    cast(g1fWih, w1f_bf, G2v*Dv);
    cast(g1bWih, w1b_bf, G2v*Dv);
    float* leafs = h_b;
    gemm_bt_kernel<float,false><<<dim3(N1v/64, Dv/64), 256, 0, stream>>>(feature, treeW_bf, treeb, h_a, leafs, Dv, Dv);
    gemm_bt_kernel<bf16_t,false><<<dim3(N1v/64, G2v/64), 256, 0, stream>>>(leafs, w1f_bf, g1fbih, nullptr, xg1f, G2v, Dv);
    gemm_bt_kernel<bf16_t,false><<<dim3(N1v/64, G2v/64), 256, 0, stream>>>(leafs, w1b_bf, g1bbih, nullptr, xg1b, G2v, Dv);

    // ---- stage 2: persistent bidirectional GRU (sub written in-kernel) ----
    cast(g1fWhh, u1f_bf, G2v*H1v);
    cast(g1bWhh, u1b_bf, G2v*H1v);
    gru1_seq_kernel<<<dim3(BKv/32, H1v/32, 2), 256, 0, stream>>>(
        h1f_a, h1f_b, h1b_a, h1b_b, u1f_bf, u1b_bf, xg1f, xg1b, g1fbhh, g1bbhh, sub, bars2);

    // ---- stage 3: input projections + persistent LSTM ----
    cast(lfWih, lwf_bf, G3v*Dv);
    cast(lbWih, lwb_bf, G3v*Dv);
    gemm_bt_kernel<bf16_t,false><<<dim3(BKv/64, G3v/64), 256, 0, stream>>>(sub, lwf_bf, lfbih, nullptr, xg2f, G3v, Dv);
    gemm_bt_kernel<bf16_t,false><<<dim3(BKv/64, G3v/64), 256, 0, stream>>>(sub, lwb_bf, lbbih, nullptr, xg2b, G3v, Dv);
    cast(lfWhh, lWf_bf, G3v*H1v);
    cast(lbWhh, lWb_bf, G3v*H1v);
    lstm_seq_kernel<<<dim3(H1v/64, 2), 256, 0, stream>>>(
        lhf_a, lhf_b, lhb_a, lhb_b, lWf_bf, lWb_bf, xg2f, xg2b, lfbhh, lbbhh, tempmax, bars3);

    // ---- head (M padded to 64; pad rows zeroed each call) ----
    bn_kernel<<<(Dv+255)/256, 256, 0, stream>>>(tempmax, bn1g, bn1b, hb1, Dv);
    cast(d1W, d1W_bf, G3v*Dv);
    gemm_bt_kernel<float,true><<<dim3(1, G3v/64), 256, 0, stream>>>(hb1, d1W_bf, d1b, nullptr, hd1, G3v, Dv);
    bn_kernel<<<(G3v+255)/256, 256, 0, stream>>>(hd1, bn2g, bn2b, hb2, G3v);
    cast(d2W, d2W_bf, Dv*G3v);
    gemm_bt_kernel<float,true><<<dim3(1, Dv/64), 256, 0, stream>>>(hb2, d2W_bf, d2b, nullptr, hd2, Dv, G3v);
    out_kernel<<<Bv, 64, 0, stream>>>(hd2, outW, outb, out);
}